// Round 2
// baseline (17095.003 us; speedup 1.0000x reference)
//
#include <hip/hip_runtime.h>
#include <hip/hip_bf16.h>
#include <math.h>

// Problem constants
#define B_ 256
#define S_ 128
#define F_ 128
#define H_ 512
#define A_ 512
#define C_ 128

#define DOT4(va, vb) ((va).x*(vb).x + (va).y*(vb).y + (va).z*(vb).z + (va).w*(vb).w)

__global__ void zero_buf(float* __restrict__ p, int n) {
    int i = blockIdx.x * 256 + threadIdx.x;
    if (i < n) p[i] = 0.f;
}

// Fused GRU step: computes gi = x_t @ Wih^T, gh = h @ Whh^T, applies gate math,
// writes h_new (and optionally the encoder-output slot).
// grid (8, 32): x = b-tile (BM=32), y = j-tile (BN=16). 256 threads.
__global__ __launch_bounds__(256)
void gru_step(const float* __restrict__ xin, int xstride,
              const float* __restrict__ hin,
              const float* __restrict__ Wih, const float* __restrict__ Whh,
              const float* __restrict__ bih, const float* __restrict__ bhh,
              float* __restrict__ hout,
              float* __restrict__ encout, int enc_bstride)
{
    const int tid = threadIdx.x;
    const int jl = tid & 15;        // 0..15 (hidden)
    const int bl = tid >> 4;        // 0..15 (batch)
    const int b0 = blockIdx.x * 32;
    const int j0 = blockIdx.y * 16;

    // k-outer float4 layout: conflict-free vector LDS reads
    __shared__ float4 sIn[8 * 32];   // [kv][row]
    __shared__ float4 sW[8 * 48];    // [kv][gate*16 + j]

    float accr[2] = {0.f, 0.f}, accz[2] = {0.f, 0.f};
    float accin[2] = {0.f, 0.f}, acchn[2] = {0.f, 0.f};

    // ---- phase A: input x (K=F=128), weights Wih ----
    for (int kc = 0; kc < F_; kc += 32) {
        {
            int r = tid >> 3, kv = tid & 7;
            sIn[kv * 32 + r] = *(const float4*)(xin + (size_t)(b0 + r) * xstride + kc + kv * 4);
        }
        for (int idx = tid; idx < 384; idx += 256) {
            int r = idx >> 3, kv = idx & 7;
            int g = r >> 4, jj = r & 15;
            sW[kv * 48 + r] = *(const float4*)(Wih + (size_t)(g * H_ + j0 + jj) * F_ + kc + kv * 4);
        }
        __syncthreads();
#pragma unroll
        for (int kk = 0; kk < 8; ++kk) {
            float4 in0 = sIn[kk * 32 + bl];
            float4 in1 = sIn[kk * 32 + bl + 16];
            float4 wr = sW[kk * 48 + jl];
            float4 wz = sW[kk * 48 + 16 + jl];
            float4 wn = sW[kk * 48 + 32 + jl];
            accr[0] += DOT4(in0, wr);  accr[1] += DOT4(in1, wr);
            accz[0] += DOT4(in0, wz);  accz[1] += DOT4(in1, wz);
            accin[0] += DOT4(in0, wn); accin[1] += DOT4(in1, wn);
        }
        __syncthreads();
    }

    // ---- phase B: hidden h (K=H=512), weights Whh ----
    for (int kc = 0; kc < H_; kc += 32) {
        {
            int r = tid >> 3, kv = tid & 7;
            sIn[kv * 32 + r] = *(const float4*)(hin + (size_t)(b0 + r) * H_ + kc + kv * 4);
        }
        for (int idx = tid; idx < 384; idx += 256) {
            int r = idx >> 3, kv = idx & 7;
            int g = r >> 4, jj = r & 15;
            sW[kv * 48 + r] = *(const float4*)(Whh + (size_t)(g * H_ + j0 + jj) * H_ + kc + kv * 4);
        }
        __syncthreads();
#pragma unroll
        for (int kk = 0; kk < 8; ++kk) {
            float4 in0 = sIn[kk * 32 + bl];
            float4 in1 = sIn[kk * 32 + bl + 16];
            float4 wr = sW[kk * 48 + jl];
            float4 wz = sW[kk * 48 + 16 + jl];
            float4 wn = sW[kk * 48 + 32 + jl];
            accr[0] += DOT4(in0, wr);  accr[1] += DOT4(in1, wr);
            accz[0] += DOT4(in0, wz);  accz[1] += DOT4(in1, wz);
            acchn[0] += DOT4(in0, wn); acchn[1] += DOT4(in1, wn);
        }
        __syncthreads();
    }

    // ---- epilogue: gate math ----
    const int j = j0 + jl;
    const float br = bih[j] + bhh[j];
    const float bz = bih[H_ + j] + bhh[H_ + j];
    const float bin_ = bih[2 * H_ + j];
    const float bhn = bhh[2 * H_ + j];
#pragma unroll
    for (int o = 0; o < 2; ++o) {
        int b = b0 + bl + o * 16;
        float r = 1.f / (1.f + expf(-(accr[o] + br)));
        float z = 1.f / (1.f + expf(-(accz[o] + bz)));
        float n = tanhf(accin[o] + bin_ + r * (acchn[o] + bhn));
        float hold = hin[(size_t)b * H_ + j];
        float hnew = (1.f - z) * n + z * hold;
        hout[(size_t)b * H_ + j] = hnew;
        if (encout) encout[(size_t)b * enc_bstride + j] = hnew;
    }
}

// C[m][n] = sum_k A[m*K+k] * Bw[n*K+k]   (A row-major [M,K], Bw row-major [N,K])
template<int BM, int BN, int TM, int TN>
__global__ __launch_bounds__(256)
void gemm_nt(const float* __restrict__ A, const float* __restrict__ Bw,
             float* __restrict__ C, int M, int N, int K)
{
    constexpr int KC = 32;
    constexpr int TX = BN / TN;   // threads in n
    constexpr int TY = BM / TM;   // threads in m  (TX*TY == 256)
    __shared__ float4 sA[(KC / 4) * BM];
    __shared__ float4 sB[(KC / 4) * BN];

    const int tid = threadIdx.x;
    const int tx = tid % TX, ty = tid / TX;
    const int m0 = blockIdx.y * BM, n0 = blockIdx.x * BN;

    float acc[TM][TN];
#pragma unroll
    for (int i = 0; i < TM; i++)
#pragma unroll
        for (int jj = 0; jj < TN; jj++) acc[i][jj] = 0.f;

    for (int kc = 0; kc < K; kc += KC) {
        for (int idx = tid; idx < BM * 8; idx += 256) {
            int r = idx >> 3, kv = idx & 7;
            sA[kv * BM + r] = *(const float4*)(A + (size_t)(m0 + r) * K + kc + kv * 4);
        }
        for (int idx = tid; idx < BN * 8; idx += 256) {
            int r = idx >> 3, kv = idx & 7;
            sB[kv * BN + r] = *(const float4*)(Bw + (size_t)(n0 + r) * K + kc + kv * 4);
        }
        __syncthreads();
#pragma unroll
        for (int kk = 0; kk < KC / 4; ++kk) {
            float4 af[TM], bf[TN];
#pragma unroll
            for (int i = 0; i < TM; i++) af[i] = sA[kk * BM + ty + i * TY];
#pragma unroll
            for (int jj = 0; jj < TN; jj++) bf[jj] = sB[kk * BN + tx + jj * TX];
#pragma unroll
            for (int i = 0; i < TM; i++)
#pragma unroll
                for (int jj = 0; jj < TN; jj++)
                    acc[i][jj] += DOT4(af[i], bf[jj]);
        }
        __syncthreads();
    }
#pragma unroll
    for (int i = 0; i < TM; i++)
#pragma unroll
        for (int jj = 0; jj < TN; jj++)
            C[(size_t)(m0 + ty + i * TY) * N + n0 + tx + jj * TX] = acc[i][jj];
}

// One block per batch element: attention scores over all S, softmax, log_softmax
// loss term, argmax (first-occurrence), gather next decoder input.
__global__ __launch_bounds__(256)
void attn_step(const float* __restrict__ ep, const float* __restrict__ hw2,
               const float* __restrict__ v, const int* __restrict__ y,
               int step, const float* __restrict__ x,
               float* __restrict__ dec_in, float* __restrict__ nlogp,
               float* __restrict__ preds_out)
{
    const int b = blockIdx.x;
    const int tid = threadIdx.x;
    __shared__ float sH[A_], sV[A_], sScore[S_], sProb[S_];
    __shared__ int sPred;

    sH[tid] = hw2[(size_t)b * A_ + tid];
    sH[tid + 256] = hw2[(size_t)b * A_ + tid + 256];
    sV[tid] = v[tid];
    sV[tid + 256] = v[tid + 256];
    __syncthreads();

    const int wv = tid >> 6, ln = tid & 63;
    const float* epb = ep + (size_t)b * S_ * A_;
    for (int si = 0; si < S_ / 4; ++si) {
        int s = si * 4 + wv;
        const float* row = epb + (size_t)s * A_ + ln * 8;
        float4 p0 = *(const float4*)(row);
        float4 p1 = *(const float4*)(row + 4);
        int a0 = ln * 8;
        float acc = fmaxf(p0.x + sH[a0 + 0], 0.f) * sV[a0 + 0]
                  + fmaxf(p0.y + sH[a0 + 1], 0.f) * sV[a0 + 1]
                  + fmaxf(p0.z + sH[a0 + 2], 0.f) * sV[a0 + 2]
                  + fmaxf(p0.w + sH[a0 + 3], 0.f) * sV[a0 + 3]
                  + fmaxf(p1.x + sH[a0 + 4], 0.f) * sV[a0 + 4]
                  + fmaxf(p1.y + sH[a0 + 5], 0.f) * sV[a0 + 5]
                  + fmaxf(p1.z + sH[a0 + 6], 0.f) * sV[a0 + 6]
                  + fmaxf(p1.w + sH[a0 + 7], 0.f) * sV[a0 + 7];
#pragma unroll
        for (int off = 32; off; off >>= 1) acc += __shfl_down(acc, off);
        if (ln == 0) sScore[s] = acc;
    }
    __syncthreads();

    if (tid < 64) {
        float v0 = sScore[tid], v1 = sScore[tid + 64];
        // softmax over scores
        float m = fmaxf(v0, v1);
#pragma unroll
        for (int off = 32; off; off >>= 1) m = fmaxf(m, __shfl_xor(m, off));
        float e0 = expf(v0 - m), e1 = expf(v1 - m);
        float se = e0 + e1;
#pragma unroll
        for (int off = 32; off; off >>= 1) se += __shfl_xor(se, off);
        float p0 = e0 / se, p1 = e1 / se;
        sProb[tid] = p0; sProb[tid + 64] = p1;
        // log_softmax of prob (mimic jax: subtract max first)
        float pm = fmaxf(p0, p1);
#pragma unroll
        for (int off = 32; off; off >>= 1) pm = fmaxf(pm, __shfl_xor(pm, off));
        float t0 = expf(p0 - pm), t1 = expf(p1 - pm);
        float T = t0 + t1;
#pragma unroll
        for (int off = 32; off; off >>= 1) T += __shfl_xor(T, off);
        // argmax on prob, first occurrence
        float bv = p0; int bi = tid;
        if (p1 > bv) { bv = p1; bi = tid + 64; }
#pragma unroll
        for (int off = 32; off; off >>= 1) {
            float ov = __shfl_xor(bv, off);
            int oi = __shfl_xor(bi, off);
            if (ov > bv || (ov == bv && oi < bi)) { bv = ov; bi = oi; }
        }
        if (ln == 0) {
            sPred = bi;
            int yy = y[(size_t)b * C_ + step];
            float py = sProb[yy];
            nlogp[(size_t)step * B_ + b] = -(py - pm - logf(T));
            preds_out[(size_t)b * C_ + step] = (float)bi;
        }
    }
    __syncthreads();

    const int pred = sPred;
    if (tid < 32) {
        const float4* src = (const float4*)(x + ((size_t)b * S_ + pred) * F_);
        float4* dst = (float4*)(dec_in + (size_t)b * F_);
        dst[tid] = src[tid];
    }
}

__global__ void final_loss(const float* __restrict__ nlogp, float* __restrict__ out)
{
    __shared__ float part[C_];
    const int i = threadIdx.x; // 128
    float s = 0.f;
    for (int b = 0; b < B_; ++b) s += nlogp[(size_t)i * B_ + b];
    part[i] = s / (float)B_;
    __syncthreads();
    if (i == 0) {
        float t = 0.f;
        for (int k = 0; k < C_; ++k) t += part[k];
        out[0] = t / (float)B_ / (float)C_;
    }
}

extern "C" void kernel_launch(void* const* d_in, const int* in_sizes, int n_in,
                              void* d_out, int out_size, void* d_ws, size_t ws_size,
                              hipStream_t stream)
{
    (void)in_sizes; (void)n_in; (void)out_size; (void)ws_size;
    const float* x    = (const float*)d_in[0];
    const int*   y    = (const int*)d_in[1];
    const float* eWih = (const float*)d_in[2];
    const float* eWhh = (const float*)d_in[3];
    const float* ebih = (const float*)d_in[4];
    const float* ebhh = (const float*)d_in[5];
    const float* dWih = (const float*)d_in[6];
    const float* dWhh = (const float*)d_in[7];
    const float* dbih = (const float*)d_in[8];
    const float* dbhh = (const float*)d_in[9];
    const float* w1   = (const float*)d_in[10];
    const float* w2   = (const float*)d_in[11];
    const float* v    = (const float*)d_in[12];
    float* out = (float*)d_out;

    float* ws = (float*)d_ws;
    float* enc_out  = ws;                       // B*S*H = 16777216
    float* enc_proj = enc_out + 16777216;       // B*S*A = 16777216
    float* hbuf0    = enc_proj + 16777216;      // B*H = 131072
    float* hbuf1    = hbuf0 + 131072;
    float* hw2buf   = hbuf1 + 131072;           // B*A = 131072
    float* dec_in   = hw2buf + 131072;          // B*F = 32768
    float* nlogp    = dec_in + 32768;           // C*B = 32768
    float* hb[2] = { hbuf0, hbuf1 };

    zero_buf<<<dim3(512), 256, 0, stream>>>(hbuf0, 131072);
    zero_buf<<<dim3(128), 256, 0, stream>>>(dec_in, 32768);

    // ---- encoder ----
    for (int t = 0; t < S_; ++t) {
        gru_step<<<dim3(8, 32), 256, 0, stream>>>(
            x + (size_t)t * F_, S_ * F_, hb[t & 1],
            eWih, eWhh, ebih, ebhh,
            hb[(t + 1) & 1],
            enc_out + (size_t)t * H_, S_ * H_);
    }

    // ---- enc_proj = enc_out @ w1^T ----
    gemm_nt<64, 64, 4, 4><<<dim3(A_ / 64, (B_ * S_) / 64), 256, 0, stream>>>(
        enc_out, w1, enc_proj, B_ * S_, A_, H_);

    // ---- decoder ----
    for (int i = 0; i < C_; ++i) {
        gru_step<<<dim3(8, 32), 256, 0, stream>>>(
            dec_in, F_, hb[i & 1],
            dWih, dWhh, dbih, dbhh,
            hb[(i + 1) & 1], (float*)nullptr, 0);
        gemm_nt<32, 64, 2, 4><<<dim3(A_ / 64, B_ / 32), 256, 0, stream>>>(
            hb[(i + 1) & 1], w2, hw2buf, B_, A_, H_);
        attn_step<<<dim3(B_), 256, 0, stream>>>(
            enc_proj, hw2buf, v, y, i, x, dec_in, nlogp, out);
    }

    final_loss<<<dim3(1), 128, 0, stream>>>(nlogp, out + (size_t)B_ * C_);
}